// Round 11
// baseline (182.199 us; speedup 1.0000x reference)
//
#include <hip/hip_runtime.h>
#include <hip/hip_bf16.h>
#include <cmath>

typedef unsigned short u16;
typedef __attribute__((ext_vector_type(8))) short short8;
typedef __attribute__((ext_vector_type(4))) float floatx4;
typedef __attribute__((ext_vector_type(4))) int intx4;
typedef __attribute__((ext_vector_type(2))) unsigned int uintx2;

#define NH     16
#define DHEAD  64
#define NSEQ   2048
#define DMODEL 1024
#define NBATCH 2
#define MTOT   (NBATCH * NSEQ)          // 4096
#define XN     ((size_t)MTOT * DMODEL)  // 4 Mi elems
#define WN     ((size_t)DMODEL * DMODEL)// 1 Mi elems

// softmax scale folded with log2(e): dh^-0.5 * 1.4426950408889634
#define QSCALE 0.18033688011118545f

__device__ inline u16 f2bf(float f) {
    unsigned int u = __builtin_bit_cast(unsigned int, f);
    unsigned int rounding = 0x7FFFu + ((u >> 16) & 1u);
    return (u16)((u + rounding) >> 16);
}

// round-half-up pack of two fp32 -> packed bf16x2 (3 VALU: 2 add + v_perm)
__device__ inline unsigned int pkbf(float a, float b) {
    unsigned int ua = __builtin_bit_cast(unsigned int, a) + 0x8000u;
    unsigned int ub = __builtin_bit_cast(unsigned int, b) + 0x8000u;
    return __builtin_amdgcn_perm(ub, ua, 0x07060302u);  // [a.hi16, b.hi16]
}

__device__ inline float fexp2(float x) {
#if __has_builtin(__builtin_amdgcn_exp2f)
    return __builtin_amdgcn_exp2f(x);
#else
    return exp2f(x);
#endif
}
__device__ inline float frcp(float x) {
#if __has_builtin(__builtin_amdgcn_rcpf)
    return __builtin_amdgcn_rcpf(x);
#else
    return 1.0f / x;
#endif
}

// within-64-token interleave so attn's PV^T A-fragment is one contiguous b128:
// j = 32c+16u+4Q+r  ->  j' = 32c+8Q+4u+r
__device__ inline int jperm(int j) {
    return (j & 32) + ((j & 12) << 1) + ((j & 16) >> 2) + (j & 3);
}

__device__ inline short8 ld8(const float* p) {
    floatx4 a = *(const floatx4*)p;
    floatx4 b = *(const floatx4*)(p + 4);
    short8 r;
    r[0] = (short)f2bf(a[0]); r[1] = (short)f2bf(a[1]);
    r[2] = (short)f2bf(a[2]); r[3] = (short)f2bf(a[3]);
    r[4] = (short)f2bf(b[0]); r[5] = (short)f2bf(b[1]);
    r[6] = (short)f2bf(b[2]); r[7] = (short)f2bf(b[3]);
    return r;
}
__device__ inline short8 ld8(const u16* p) { return *(const short8*)p; }

__device__ inline void gl_lds16(const u16* g, short* l) {
    __builtin_amdgcn_global_load_lds(
        (const __attribute__((address_space(1))) unsigned int*)(const void*)g,
        (__attribute__((address_space(3))) unsigned int*)(void*)l, 16, 0, 0);
}

// ---------------------------------------------------------------------------
// fp32 -> bf16 conversion for x, Wq, Wk, Wv, Wo (one pass)
// ---------------------------------------------------------------------------
__global__ __launch_bounds__(256) void cvt_all(const float* __restrict__ x,
                                               const float* __restrict__ wq,
                                               const float* __restrict__ wk,
                                               const float* __restrict__ wv,
                                               const float* __restrict__ wo,
                                               u16* __restrict__ xb,
                                               u16* __restrict__ wqb,
                                               u16* __restrict__ wkb,
                                               u16* __restrict__ wvb,
                                               u16* __restrict__ wob)
{
    size_t t = (size_t)blockIdx.x * 256 + threadIdx.x;
    size_t e = t * 8;
    const float* s; u16* d; size_t off;
    if (e < XN) { s = x; d = xb; off = e; }
    else {
        size_t r = (e - XN) >> 20;              // WN == 2^20
        off = (e - XN) & (WN - 1);
        s = (r == 0) ? wq : (r == 1) ? wk : (r == 2) ? wv : wo;
        d = (r == 0) ? wqb : (r == 1) ? wkb : (r == 2) ? wvb : wob;
    }
    *(short8*)&d[off] = ld8(&s[off]);
}

// ---------------------------------------------------------------------------
// QKV GEMM, operand-swapped: A = W rows (out-dim), B = x rows (tokens).
// C-layout then gives each lane 4 CONSECUTIVE d in regs -> 8B packed stores
// for Q/K ([b,h,tok,d]); V^T gets [b,h,d,tok] (jperm'd cols) as before.
// Grid: x in [0,24) = widx*8 + wtile; y in [0,32) = token tile.
// ---------------------------------------------------------------------------
__global__ __launch_bounds__(256) void gemm_qkv(const u16* __restrict__ X,
                                                const u16* __restrict__ W0,
                                                const u16* __restrict__ W1,
                                                const u16* __restrict__ W2,
                                                u16* __restrict__ C0,
                                                u16* __restrict__ C1,
                                                u16* __restrict__ C2)
{
    __shared__ __align__(16) short Ws[128 * 64];
    __shared__ __align__(16) short Xs[128 * 64];

    const int tid  = threadIdx.x;
    const int w    = tid >> 6;
    const int lane = tid & 63;
    const int ln   = lane & 15;
    const int q    = lane >> 4;
    const int lx   = ln & 7;
    const int wm   = w >> 1;
    const int wn   = w & 1;
    const int widx = blockIdx.x >> 3;
    const int w0   = (blockIdx.x & 7) * 128;   // weight-out-dim tile base
    const int t0   = blockIdx.y * 128;         // token tile base
    const u16* Wp  = (widx == 0 ? W0 : (widx == 1 ? W1 : W2));

    const int rsub = lane >> 3;
    const int kcl  = (lane & 7) ^ (rsub & 7);

    floatx4 acc[4][4];
#pragma unroll
    for (int i = 0; i < 4; ++i)
#pragma unroll
        for (int j = 0; j < 4; ++j) acc[i][j] = (floatx4){0.f, 0.f, 0.f, 0.f};

    for (int k0 = 0; k0 < DMODEL; k0 += 64) {
#pragma unroll
        for (int i = 0; i < 4; ++i) {
            const int r = (w * 4 + i) * 8 + rsub;
            gl_lds16(&Wp[(size_t)(w0 + r) * DMODEL + k0 + kcl * 8], &Ws[(w * 4 + i) * 512]);
            gl_lds16(&X [(size_t)(t0 + r) * DMODEL + k0 + kcl * 8], &Xs[(w * 4 + i) * 512]);
        }
        __syncthreads();
#pragma unroll
        for (int kk = 0; kk < 2; ++kk) {
            short8 af[4], bf[4];
#pragma unroll
            for (int t = 0; t < 4; ++t) {
                af[t] = *(short8*)&Ws[(wm * 64 + t * 16 + ln) * 64 + (((kk * 4 + q) ^ lx) * 8)];
                bf[t] = *(short8*)&Xs[(wn * 64 + t * 16 + ln) * 64 + (((kk * 4 + q) ^ lx) * 8)];
            }
#pragma unroll
            for (int mt = 0; mt < 4; ++mt)
#pragma unroll
                for (int nt = 0; nt < 4; ++nt)
                    acc[mt][nt] = __builtin_amdgcn_mfma_f32_16x16x32_bf16(af[mt], bf[nt], acc[mt][nt], 0, 0, 0);
        }
        __syncthreads();
    }

    if (widx != 2) {
        u16* Cw = (widx == 0 ? C0 : C1);
        const float os = (widx == 0) ? QSCALE : 1.0f;
#pragma unroll
        for (int mt = 0; mt < 4; ++mt) {
            const int wd0 = w0 + wm * 64 + mt * 16 + q * 4;  // 4 consecutive d
            const int h   = wd0 >> 6, dlo = wd0 & 63;
#pragma unroll
            for (int nt = 0; nt < 4; ++nt) {
                const int token = t0 + wn * 64 + nt * 16 + ln;
                const int b = token >> 11, tk = token & 2047;
                uintx2 pk;
                pk[0] = pkbf(acc[mt][nt][0] * os, acc[mt][nt][1] * os);
                pk[1] = pkbf(acc[mt][nt][2] * os, acc[mt][nt][3] * os);
                *(uintx2*)&Cw[((size_t)(b * NH + h) * NSEQ + tk) * DHEAD + dlo] = pk;
            }
        }
    } else {
#pragma unroll
        for (int mt = 0; mt < 4; ++mt) {
#pragma unroll
            for (int nt = 0; nt < 4; ++nt) {
                const int token = t0 + wn * 64 + nt * 16 + ln;
                const int b = token >> 11, tk = token & 2047;
                const int tokp = (tk & ~63) + jperm(tk & 63);
#pragma unroll
                for (int reg = 0; reg < 4; ++reg) {
                    const int wd = w0 + wm * 64 + mt * 16 + q * 4 + reg;
                    const int h = wd >> 6, d = wd & 63;
                    C2[((size_t)(b * NH + h) * DHEAD + d) * NSEQ + tokp] = f2bf(acc[mt][nt][reg]);
                }
            }
        }
    }
}

// ---------------------------------------------------------------------------
// O-projection GEMM, operand-swapped: A = Wo rows (64-tile), B = O tokens
// (128-tile). Lane holds 4 consecutive out-cols -> float4 stores + float4 bias.
// Grid (32 token-tiles, 16 wdim-tiles) = 512 blocks.
// ---------------------------------------------------------------------------
__global__ __launch_bounds__(256) void gemm_op(const u16* __restrict__ Wo,
                                               const u16* __restrict__ O,
                                               const float* __restrict__ bias,
                                               float* __restrict__ C)
{
    __shared__ __align__(16) short As[64 * 64];    // Wo rows
    __shared__ __align__(16) short Bs[128 * 64];   // O token rows

    const int tid  = threadIdx.x;
    const int w    = tid >> 6;
    const int lane = tid & 63;
    const int ln   = lane & 15;
    const int q    = lane >> 4;
    const int lx   = ln & 7;
    const int wm   = w >> 1;
    const int wn   = w & 1;
    const int m0   = blockIdx.y * 64;    // wdim tile
    const int n0   = blockIdx.x * 128;   // token tile

    const int rsub = lane >> 3;
    const int kcl  = (lane & 7) ^ (rsub & 7);

    floatx4 acc[2][4];
#pragma unroll
    for (int i = 0; i < 2; ++i)
#pragma unroll
        for (int j = 0; j < 4; ++j) acc[i][j] = (floatx4){0.f, 0.f, 0.f, 0.f};

    for (int k0 = 0; k0 < DMODEL; k0 += 64) {
#pragma unroll
        for (int i = 0; i < 2; ++i) {
            const int c = w * 2 + i;
            gl_lds16(&Wo[(size_t)(m0 + c * 8 + rsub) * DMODEL + k0 + kcl * 8], &As[c * 512]);
        }
#pragma unroll
        for (int i = 0; i < 4; ++i) {
            const int c = w * 4 + i;
            gl_lds16(&O[(size_t)(n0 + c * 8 + rsub) * DMODEL + k0 + kcl * 8], &Bs[c * 512]);
        }
        __syncthreads();
#pragma unroll
        for (int kk = 0; kk < 2; ++kk) {
            short8 af[2], bf[4];
#pragma unroll
            for (int t = 0; t < 2; ++t)
                af[t] = *(short8*)&As[(wm * 32 + t * 16 + ln) * 64 + (((kk * 4 + q) ^ lx) * 8)];
#pragma unroll
            for (int t = 0; t < 4; ++t)
                bf[t] = *(short8*)&Bs[(wn * 64 + t * 16 + ln) * 64 + (((kk * 4 + q) ^ lx) * 8)];
#pragma unroll
            for (int mt = 0; mt < 2; ++mt)
#pragma unroll
                for (int nt = 0; nt < 4; ++nt)
                    acc[mt][nt] = __builtin_amdgcn_mfma_f32_16x16x32_bf16(af[mt], bf[nt], acc[mt][nt], 0, 0, 0);
        }
        __syncthreads();
    }

#pragma unroll
    for (int mt = 0; mt < 2; ++mt) {
        const int wd0 = m0 + wm * 32 + mt * 16 + q * 4;   // 4 consecutive cols
        const floatx4 bv = *(const floatx4*)&bias[wd0];
#pragma unroll
        for (int nt = 0; nt < 4; ++nt) {
            const int token = n0 + wn * 64 + nt * 16 + ln;
            floatx4 v = acc[mt][nt] + bv;
            *(floatx4*)&C[(size_t)token * DMODEL + wd0] = v;
        }
    }
}

// ---------------------------------------------------------------------------
// attn7: kt-split flash attention (see R9). Added: unroll-2 on the kt loop so
// the double-buffer index `cur` folds to literals (address VALU savings).
// ---------------------------------------------------------------------------
__global__ __launch_bounds__(512) void attn7(const u16* __restrict__ Q,
                                             const u16* __restrict__ K,
                                             const u16* __restrict__ Vt,
                                             u16* __restrict__ O)
{
    __shared__ __align__(16) short Kb[2][2][64 * 64];  // [g][buf] 32 KB
    __shared__ __align__(16) short Vb[2][2][64 * 64];  // [g][buf] 32 KB

    const int tid  = threadIdx.x;
    const int w    = tid >> 6;
    const int g    = w >> 2;         // kt-half
    const int wl   = w & 3;          // wave-in-group
    const int lane = tid & 63;
    const int ln   = lane & 15;
    const int q    = lane >> 4;
    const int lx   = ln & 7;
    const int bid  = blockIdx.x;
    const int bh   = bid & 31;
    const int qt   = bid >> 5;                // 0..15
    const int row0 = qt * 128 + wl * 32;
    const size_t sbase = (size_t)bh * NSEQ;
    const size_t vbase = (size_t)bh * DHEAD;
    const int kt0 = g * 16;

    const int rsub = lane >> 3;
    const int swz  = (lane & 7) ^ (rsub & 7);

    const intx4 onesi = {0x3F803F80, 0x3F803F80, 0x3F803F80, 0x3F803F80};
    const short8 ones = __builtin_bit_cast(short8, onesi);

    short8 bq[2][2];
#pragma unroll
    for (int mt = 0; mt < 2; ++mt)
#pragma unroll
        for (int kk = 0; kk < 2; ++kk)
            bq[mt][kk] = *(const short8*)&Q[(sbase + row0 + mt * 16 + ln) * DHEAD + kk * 32 + q * 8];

    floatx4 zero = {0.f, 0.f, 0.f, 0.f};
    floatx4 o[2][4];
    floatx4 ol[2];
#pragma unroll
    for (int mt = 0; mt < 2; ++mt) {
        ol[mt] = zero;
#pragma unroll
        for (int dt = 0; dt < 4; ++dt) o[mt][dt] = zero;
    }

    // stage this group's tile 0
#pragma unroll
    for (int i = 0; i < 2; ++i) {
        const int c = wl * 2 + i;
        const int row = c * 8 + rsub;
        gl_lds16(&K [(sbase + kt0 * 64 + row) * DHEAD + swz * 8], &Kb[g][0][c * 512]);
        gl_lds16(&Vt[(vbase + row) * NSEQ + kt0 * 64 + swz * 8],  &Vb[g][0][c * 512]);
    }

#pragma unroll 2
    for (int it = 0; it < 16; ++it) {
        __syncthreads();
        const int cur = it & 1;
        if (it + 1 < 16) {
            const int kb = (kt0 + it + 1) * 64;
#pragma unroll
            for (int i = 0; i < 2; ++i) {
                const int c = wl * 2 + i;
                const int row = c * 8 + rsub;
                gl_lds16(&K [(sbase + kb + row) * DHEAD + swz * 8], &Kb[g][cur ^ 1][c * 512]);
                gl_lds16(&Vt[(vbase + row) * NSEQ + kb + swz * 8],  &Vb[g][cur ^ 1][c * 512]);
            }
        }

        floatx4 st[4][2];
#pragma unroll
        for (int t = 0; t < 4; ++t) {
            short8 ak0 = *(short8*)&Kb[g][cur][(t * 16 + ln) * 64 + ((q ^ lx) * 8)];
            short8 ak1 = *(short8*)&Kb[g][cur][(t * 16 + ln) * 64 + (((4 + q) ^ lx) * 8)];
#pragma unroll
            for (int mt = 0; mt < 2; ++mt) {
                st[t][mt] = zero;
                st[t][mt] = __builtin_amdgcn_mfma_f32_16x16x32_bf16(ak0, bq[mt][0], st[t][mt], 0, 0, 0);
                st[t][mt] = __builtin_amdgcn_mfma_f32_16x16x32_bf16(ak1, bq[mt][1], st[t][mt], 0, 0, 0);
            }
        }

        intx4 bp[2][2];
#pragma unroll
        for (int mt = 0; mt < 2; ++mt) {
#pragma unroll
            for (int t = 0; t < 4; ++t) {
                floatx4 p;
#pragma unroll
                for (int r = 0; r < 4; ++r) p[r] = fexp2(st[t][mt][r]);
                bp[t >> 1][mt][(t & 1) * 2 + 0] = (int)pkbf(p[0], p[1]);
                bp[t >> 1][mt][(t & 1) * 2 + 1] = (int)pkbf(p[2], p[3]);
            }
        }

#pragma unroll
        for (int mt = 0; mt < 2; ++mt)
#pragma unroll
            for (int c = 0; c < 2; ++c)
                ol[mt] = __builtin_amdgcn_mfma_f32_16x16x32_bf16(
                    ones, __builtin_bit_cast(short8, bp[c][mt]), ol[mt], 0, 0, 0);

#pragma unroll
        for (int dt = 0; dt < 4; ++dt) {
#pragma unroll
            for (int c = 0; c < 2; ++c) {
                short8 av = *(short8*)&Vb[g][cur][(dt * 16 + ln) * 64 + (((4 * c + q) ^ lx) * 8)];
#pragma unroll
                for (int mt = 0; mt < 2; ++mt)
                    o[mt][dt] = __builtin_amdgcn_mfma_f32_16x16x32_bf16(
                        av, __builtin_bit_cast(short8, bp[c][mt]), o[mt][dt], 0, 0, 0);
            }
        }
    }

    // ---- combine the two kt-halves via LDS (exact: plain sums) ----
    __syncthreads();
    float* of = (float*)&Kb[0][0][0];
    float* lf = (float*)&Vb[1][1][0];
    if (g == 1) {
#pragma unroll
        for (int mt = 0; mt < 2; ++mt) {
#pragma unroll
            for (int dt = 0; dt < 4; ++dt)
                *(floatx4*)&of[(wl * 32 + mt * 16 + ln) * 68 + dt * 16 + q * 4] = o[mt][dt];
            lf[wl * 32 + mt * 16 + ln] = ol[mt][0];
        }
    }
    __syncthreads();
    if (g == 0) {
        const int b = bh >> 4, h = bh & 15;
        float l[2];
#pragma unroll
        for (int mt = 0; mt < 2; ++mt)
            l[mt] = frcp(ol[mt][0] + lf[wl * 32 + mt * 16 + ln]);
#pragma unroll
        for (int mt = 0; mt < 2; ++mt) {
            const int tok = row0 + mt * 16 + ln;
#pragma unroll
            for (int dt = 0; dt < 4; ++dt) {
                floatx4 p = *(floatx4*)&of[(wl * 32 + mt * 16 + ln) * 68 + dt * 16 + q * 4];
                uintx2 pk;
                pk[0] = pkbf((o[mt][dt][0] + p[0]) * l[mt], (o[mt][dt][1] + p[1]) * l[mt]);
                pk[1] = pkbf((o[mt][dt][2] + p[2]) * l[mt], (o[mt][dt][3] + p[3]) * l[mt]);
                *(uintx2*)&O[((size_t)(b * NSEQ + tok)) * DMODEL + h * DHEAD + dt * 16 + q * 4] = pk;
            }
        }
    }
}

// ---------------------------------------------------------------------------
// Fallback small-tile GEMM (fp32 staging) — used only if ws too small.
// ---------------------------------------------------------------------------
template <int MODE, typename TA, typename TB>
__global__ __launch_bounds__(256) void gemm_bt(const TA* __restrict__ A,
                                               const TB* __restrict__ B,
                                               const float* __restrict__ bias,
                                               void* __restrict__ Cv,
                                               float oscale)
{
    __shared__ __align__(16) short As[64][72];
    __shared__ __align__(16) short Bs[64][72];

    const int tid  = threadIdx.x;
    const int w    = tid >> 6;
    const int lane = tid & 63;
    const int ln   = lane & 15;
    const int q    = lane >> 4;
    const int wm   = w >> 1;
    const int wn   = w & 1;
    const int m0   = blockIdx.y * 64;
    const int n0   = blockIdx.x * 64;
    const int r    = tid >> 3;
    const int c8   = (tid & 7) * 8;

    floatx4 zero = {0.f, 0.f, 0.f, 0.f};
    floatx4 acc[2][2];
    acc[0][0] = zero; acc[0][1] = zero; acc[1][0] = zero; acc[1][1] = zero;

    for (int k0 = 0; k0 < DMODEL; k0 += 64) {
        *(short8*)&As[r][c8]      = ld8(&A[(size_t)(m0 + r) * DMODEL + k0 + c8]);
        *(short8*)&As[r + 32][c8] = ld8(&A[(size_t)(m0 + r + 32) * DMODEL + k0 + c8]);
        *(short8*)&Bs[r][c8]      = ld8(&B[(size_t)(n0 + r) * DMODEL + k0 + c8]);
        *(short8*)&Bs[r + 32][c8] = ld8(&B[(size_t)(n0 + r + 32) * DMODEL + k0 + c8]);
        __syncthreads();
#pragma unroll
        for (int kk = 0; kk < 2; ++kk) {
            short8 a0 = *(short8*)&As[wm * 32 + ln][kk * 32 + q * 8];
            short8 a1 = *(short8*)&As[wm * 32 + 16 + ln][kk * 32 + q * 8];
            short8 b0 = *(short8*)&Bs[wn * 32 + ln][kk * 32 + q * 8];
            short8 b1 = *(short8*)&Bs[wn * 32 + 16 + ln][kk * 32 + q * 8];
            acc[0][0] = __builtin_amdgcn_mfma_f32_16x16x32_bf16(a0, b0, acc[0][0], 0, 0, 0);
            acc[0][1] = __builtin_amdgcn_mfma_f32_16x16x32_bf16(a0, b1, acc[0][1], 0, 0, 0);
            acc[1][0] = __builtin_amdgcn_mfma_f32_16x16x32_bf16(a1, b0, acc[1][0], 0, 0, 0);
            acc[1][1] = __builtin_amdgcn_mfma_f32_16x16x32_bf16(a1, b1, acc[1][1], 0, 0, 0);
        }
        __syncthreads();
    }

#pragma unroll
    for (int mt = 0; mt < 2; ++mt) {
#pragma unroll
        for (int nt = 0; nt < 2; ++nt) {
            const int coln = wn * 32 + nt * 16 + ln;
            float bval = 0.f;
            if (MODE == 0) bval = bias[n0 + coln];
#pragma unroll
            for (int reg = 0; reg < 4; ++reg) {
                const int grow = m0 + wm * 32 + mt * 16 + q * 4 + reg;
                const float v = acc[mt][nt][reg] * oscale + bval;
                if (MODE == 0) {
                    ((float*)Cv)[(size_t)grow * DMODEL + n0 + coln] = v;
                } else {
                    const int b = grow >> 11, tok = grow & 2047, h = n0 >> 6;
                    if (MODE == 1)
                        ((u16*)Cv)[((size_t)(b * NH + h) * NSEQ + tok) * DHEAD + coln] = f2bf(v);
                    else {
                        const int tokp = (tok & ~63) + jperm(tok & 63);
                        ((u16*)Cv)[((size_t)(b * NH + h) * DHEAD + coln) * NSEQ + tokp] = f2bf(v);
                    }
                }
            }
        }
    }
}

// ---------------------------------------------------------------------------
extern "C" void kernel_launch(void* const* d_in, const int* in_sizes, int n_in,
                              void* d_out, int out_size, void* d_ws, size_t ws_size,
                              hipStream_t stream) {
    (void)in_sizes; (void)n_in; (void)out_size;
    const float* x  = (const float*)d_in[0];
    const float* Wq = (const float*)d_in[1];
    const float* Wk = (const float*)d_in[2];
    const float* Wv = (const float*)d_in[3];
    const float* Wo = (const float*)d_in[4];
    const float* bo = (const float*)d_in[5];
    float* out = (float*)d_out;

    dim3 bb(256);
    dim3 ba(512);   // attn7 block = 8 waves
    dim3 ga(512);   // attention grid: bh = bid&31 (XCD affinity), qt = bid>>5

    const size_t NEED = XN * 2 + 4 * WN * 2 + 3 * XN * 2;
    if (ws_size >= NEED) {
        u16* xb  = (u16*)d_ws;
        u16* Wqb = xb + XN;
        u16* Wkb = Wqb + WN;
        u16* Wvb = Wkb + WN;
        u16* Wob = Wvb + WN;
        u16* Qb  = Wob + WN;
        u16* Kb  = Qb + XN;
        u16* Vtb = Kb + XN;
        u16* Ob  = xb;

        cvt_all<<<dim3((unsigned)((XN + 4 * WN) / 8 / 256)), bb, 0, stream>>>(
            x, Wq, Wk, Wv, Wo, xb, Wqb, Wkb, Wvb, Wob);

        gemm_qkv<<<dim3(24, 32), bb, 0, stream>>>(xb, Wqb, Wkb, Wvb, Qb, Kb, Vtb);
        attn7<<<ga, ba, 0, stream>>>(Qb, Kb, Vtb, Ob);
        gemm_op<<<dim3(32, 16), bb, 0, stream>>>(Wob, Ob, bo, out);
    } else {
        u16* Qb  = (u16*)d_ws;
        u16* Kb  = Qb + XN;
        u16* Vtb = Kb + XN;
        u16* Ob  = Vtb + XN;
        dim3 gg(DMODEL / 64, MTOT / 64);
        gemm_bt<1, float, float><<<gg, bb, 0, stream>>>(x, Wq, nullptr, Qb, QSCALE);
        gemm_bt<1, float, float><<<gg, bb, 0, stream>>>(x, Wk, nullptr, Kb, 1.0f);
        gemm_bt<2, float, float><<<gg, bb, 0, stream>>>(x, Wv, nullptr, Vtb, 1.0f);
        attn7<<<ga, ba, 0, stream>>>(Qb, Kb, Vtb, Ob);
        gemm_bt<0, u16, float><<<gg, bb, 0, stream>>>(Ob, Wo, bo, out, 1.0f);
    }
}

// Round 12
// 177.933 us; speedup vs baseline: 1.0240x; 1.0240x over previous
//
#include <hip/hip_runtime.h>
#include <hip/hip_bf16.h>
#include <cmath>

typedef unsigned short u16;
typedef __attribute__((ext_vector_type(8))) short short8;
typedef __attribute__((ext_vector_type(4))) float floatx4;
typedef __attribute__((ext_vector_type(4))) int intx4;
typedef __attribute__((ext_vector_type(2))) unsigned int uintx2;

#define NH     16
#define DHEAD  64
#define NSEQ   2048
#define DMODEL 1024
#define NBATCH 2
#define MTOT   (NBATCH * NSEQ)          // 4096
#define XN     ((size_t)MTOT * DMODEL)  // 4 Mi elems
#define WN     ((size_t)DMODEL * DMODEL)// 1 Mi elems

// softmax scale folded with log2(e): dh^-0.5 * 1.4426950408889634
#define QSCALE 0.18033688011118545f

__device__ inline u16 f2bf(float f) {
    unsigned int u = __builtin_bit_cast(unsigned int, f);
    unsigned int rounding = 0x7FFFu + ((u >> 16) & 1u);
    return (u16)((u + rounding) >> 16);
}

// round-half-up pack of two fp32 -> packed bf16x2 (3 VALU: 2 add + v_perm)
__device__ inline unsigned int pkbf(float a, float b) {
    unsigned int ua = __builtin_bit_cast(unsigned int, a) + 0x8000u;
    unsigned int ub = __builtin_bit_cast(unsigned int, b) + 0x8000u;
    return __builtin_amdgcn_perm(ub, ua, 0x07060302u);  // [a.hi16, b.hi16]
}

__device__ inline float fexp2(float x) {
#if __has_builtin(__builtin_amdgcn_exp2f)
    return __builtin_amdgcn_exp2f(x);
#else
    return exp2f(x);
#endif
}
__device__ inline float frcp(float x) {
#if __has_builtin(__builtin_amdgcn_rcpf)
    return __builtin_amdgcn_rcpf(x);
#else
    return 1.0f / x;
#endif
}

// within-64-token interleave so attn's PV^T A-fragment is one contiguous b128:
// j = 32c+16u+4Q+r  ->  j' = 32c+8Q+4u+r
__device__ inline int jperm(int j) {
    return (j & 32) + ((j & 12) << 1) + ((j & 16) >> 2) + (j & 3);
}

__device__ inline short8 ld8(const float* p) {
    floatx4 a = *(const floatx4*)p;
    floatx4 b = *(const floatx4*)(p + 4);
    short8 r;
    r[0] = (short)f2bf(a[0]); r[1] = (short)f2bf(a[1]);
    r[2] = (short)f2bf(a[2]); r[3] = (short)f2bf(a[3]);
    r[4] = (short)f2bf(b[0]); r[5] = (short)f2bf(b[1]);
    r[6] = (short)f2bf(b[2]); r[7] = (short)f2bf(b[3]);
    return r;
}
__device__ inline short8 ld8(const u16* p) { return *(const short8*)p; }

__device__ inline void gl_lds16(const u16* g, short* l) {
    __builtin_amdgcn_global_load_lds(
        (const __attribute__((address_space(1))) unsigned int*)(const void*)g,
        (__attribute__((address_space(3))) unsigned int*)(void*)l, 16, 0, 0);
}

// ---------------------------------------------------------------------------
// fp32 -> bf16 conversion for x, Wq, Wk, Wv, Wo (one pass)
// ---------------------------------------------------------------------------
__global__ __launch_bounds__(256) void cvt_all(const float* __restrict__ x,
                                               const float* __restrict__ wq,
                                               const float* __restrict__ wk,
                                               const float* __restrict__ wv,
                                               const float* __restrict__ wo,
                                               u16* __restrict__ xb,
                                               u16* __restrict__ wqb,
                                               u16* __restrict__ wkb,
                                               u16* __restrict__ wvb,
                                               u16* __restrict__ wob)
{
    size_t t = (size_t)blockIdx.x * 256 + threadIdx.x;
    size_t e = t * 8;
    const float* s; u16* d; size_t off;
    if (e < XN) { s = x; d = xb; off = e; }
    else {
        size_t r = (e - XN) >> 20;              // WN == 2^20
        off = (e - XN) & (WN - 1);
        s = (r == 0) ? wq : (r == 1) ? wk : (r == 2) ? wv : wo;
        d = (r == 0) ? wqb : (r == 1) ? wkb : (r == 2) ? wvb : wob;
    }
    *(short8*)&d[off] = ld8(&s[off]);
}

// ---------------------------------------------------------------------------
// QKV GEMM, m97 structure (R10 orientation — measured faster than the R11
// operand swap): 128x128 tile, 4 waves 2x2, 4x4 acc.
// blockIdx.x<8 -> Q (scaled), <16 -> K, else V^T (operand-swapped: A=Wv, B=x,
// so output rows = d-dim and the token stores coalesce; columns jperm'd).
// ---------------------------------------------------------------------------
__global__ __launch_bounds__(256) void gemm_qkv(const u16* __restrict__ A,
                                                const u16* __restrict__ B0,
                                                const u16* __restrict__ B1,
                                                const u16* __restrict__ B2,
                                                u16* __restrict__ C0,
                                                u16* __restrict__ C1,
                                                u16* __restrict__ C2)
{
    __shared__ __align__(16) short As[128 * 64];
    __shared__ __align__(16) short Bs[128 * 64];

    const int tid  = threadIdx.x;
    const int w    = tid >> 6;
    const int lane = tid & 63;
    const int ln   = lane & 15;
    const int q    = lane >> 4;
    const int lx   = ln & 7;
    const int wm   = w >> 1;
    const int wn   = w & 1;
    const int m0   = blockIdx.y * 128;
    const int widx = blockIdx.x >> 3;
    const int col0 = (blockIdx.x & 7) * 128;
    const u16* Bp  = (widx == 0 ? B0 : (widx == 1 ? B1 : B2));

    const int rsub = lane >> 3;
    const int kcl  = (lane & 7) ^ (rsub & 7);

    floatx4 acc[4][4];
#pragma unroll
    for (int i = 0; i < 4; ++i)
#pragma unroll
        for (int j = 0; j < 4; ++j) acc[i][j] = (floatx4){0.f, 0.f, 0.f, 0.f};

    for (int k0 = 0; k0 < DMODEL; k0 += 64) {
#pragma unroll
        for (int i = 0; i < 4; ++i) {
            const int r = (w * 4 + i) * 8 + rsub;
            gl_lds16(&A [(size_t)(m0 + r)   * DMODEL + k0 + kcl * 8], &As[(w * 4 + i) * 512]);
            gl_lds16(&Bp[(size_t)(col0 + r) * DMODEL + k0 + kcl * 8], &Bs[(w * 4 + i) * 512]);
        }
        __syncthreads();
#pragma unroll
        for (int kk = 0; kk < 2; ++kk) {
            short8 af[4], bf[4];
#pragma unroll
            for (int t = 0; t < 4; ++t) {
                af[t] = *(short8*)&As[(wm * 64 + t * 16 + ln) * 64 + (((kk * 4 + q) ^ lx) * 8)];
                bf[t] = *(short8*)&Bs[(wn * 64 + t * 16 + ln) * 64 + (((kk * 4 + q) ^ lx) * 8)];
            }
            if (widx != 2) {
#pragma unroll
                for (int mt = 0; mt < 4; ++mt)
#pragma unroll
                    for (int nt = 0; nt < 4; ++nt)
                        acc[mt][nt] = __builtin_amdgcn_mfma_f32_16x16x32_bf16(af[mt], bf[nt], acc[mt][nt], 0, 0, 0);
            } else {
#pragma unroll
                for (int mt = 0; mt < 4; ++mt)
#pragma unroll
                    for (int nt = 0; nt < 4; ++nt)
                        acc[mt][nt] = __builtin_amdgcn_mfma_f32_16x16x32_bf16(bf[mt], af[nt], acc[mt][nt], 0, 0, 0);
            }
        }
        __syncthreads();
    }

    if (widx != 2) {
        u16* Cw = (widx == 0 ? C0 : C1);
        const float oscale = (widx == 0) ? QSCALE : 1.0f;
#pragma unroll
        for (int mt = 0; mt < 4; ++mt) {
#pragma unroll
            for (int nt = 0; nt < 4; ++nt) {
                const int coln = wn * 64 + nt * 16 + ln;
#pragma unroll
                for (int reg = 0; reg < 4; ++reg) {
                    const int grow = m0 + wm * 64 + mt * 16 + q * 4 + reg;
                    const float v = acc[mt][nt][reg] * oscale;
                    const int gcol = col0 + coln;
                    const int h = gcol >> 6, d = gcol & 63;
                    const int b = grow >> 11, tok = grow & 2047;
                    Cw[((size_t)(b * NH + h) * NSEQ + tok) * DHEAD + d] = f2bf(v);
                }
            }
        }
    } else {
#pragma unroll
        for (int mt = 0; mt < 4; ++mt) {
#pragma unroll
            for (int nt = 0; nt < 4; ++nt) {
                const int tokg = m0 + wm * 64 + nt * 16 + ln;
                const int b = tokg >> 11, tok = tokg & 2047;
                const int tokp = (tok & ~63) + jperm(tok & 63);
#pragma unroll
                for (int reg = 0; reg < 4; ++reg) {
                    const int gcol = col0 + wn * 64 + mt * 16 + q * 4 + reg;
                    const int h = gcol >> 6, d = gcol & 63;
                    C2[((size_t)(b * NH + h) * DHEAD + d) * NSEQ + tokp] = f2bf(acc[mt][nt][reg]);
                }
            }
        }
    }
}

// ---------------------------------------------------------------------------
// O-projection GEMM, operand-swapped (R11 — measured faster): A = Wo rows
// (64-tile), B = O tokens (128-tile). Lane holds 4 consecutive out-cols ->
// float4 stores + float4 bias. Grid (32 token-tiles, 16 wdim-tiles).
// ---------------------------------------------------------------------------
__global__ __launch_bounds__(256) void gemm_op(const u16* __restrict__ Wo,
                                               const u16* __restrict__ O,
                                               const float* __restrict__ bias,
                                               float* __restrict__ C)
{
    __shared__ __align__(16) short As[64 * 64];    // Wo rows
    __shared__ __align__(16) short Bs[128 * 64];   // O token rows

    const int tid  = threadIdx.x;
    const int w    = tid >> 6;
    const int lane = tid & 63;
    const int ln   = lane & 15;
    const int q    = lane >> 4;
    const int lx   = ln & 7;
    const int wm   = w >> 1;
    const int wn   = w & 1;
    const int m0   = blockIdx.y * 64;    // wdim tile
    const int n0   = blockIdx.x * 128;   // token tile

    const int rsub = lane >> 3;
    const int kcl  = (lane & 7) ^ (rsub & 7);

    floatx4 acc[2][4];
#pragma unroll
    for (int i = 0; i < 2; ++i)
#pragma unroll
        for (int j = 0; j < 4; ++j) acc[i][j] = (floatx4){0.f, 0.f, 0.f, 0.f};

    for (int k0 = 0; k0 < DMODEL; k0 += 64) {
#pragma unroll
        for (int i = 0; i < 2; ++i) {
            const int c = w * 2 + i;
            gl_lds16(&Wo[(size_t)(m0 + c * 8 + rsub) * DMODEL + k0 + kcl * 8], &As[c * 512]);
        }
#pragma unroll
        for (int i = 0; i < 4; ++i) {
            const int c = w * 4 + i;
            gl_lds16(&O[(size_t)(n0 + c * 8 + rsub) * DMODEL + k0 + kcl * 8], &Bs[c * 512]);
        }
        __syncthreads();
#pragma unroll
        for (int kk = 0; kk < 2; ++kk) {
            short8 af[2], bf[4];
#pragma unroll
            for (int t = 0; t < 2; ++t)
                af[t] = *(short8*)&As[(wm * 32 + t * 16 + ln) * 64 + (((kk * 4 + q) ^ lx) * 8)];
#pragma unroll
            for (int t = 0; t < 4; ++t)
                bf[t] = *(short8*)&Bs[(wn * 64 + t * 16 + ln) * 64 + (((kk * 4 + q) ^ lx) * 8)];
#pragma unroll
            for (int mt = 0; mt < 2; ++mt)
#pragma unroll
                for (int nt = 0; nt < 4; ++nt)
                    acc[mt][nt] = __builtin_amdgcn_mfma_f32_16x16x32_bf16(af[mt], bf[nt], acc[mt][nt], 0, 0, 0);
        }
        __syncthreads();
    }

#pragma unroll
    for (int mt = 0; mt < 2; ++mt) {
        const int wd0 = m0 + wm * 32 + mt * 16 + q * 4;   // 4 consecutive cols
        const floatx4 bv = *(const floatx4*)&bias[wd0];
#pragma unroll
        for (int nt = 0; nt < 4; ++nt) {
            const int token = n0 + wn * 64 + nt * 16 + ln;
            floatx4 v = acc[mt][nt] + bv;
            *(floatx4*)&C[(size_t)token * DMODEL + wd0] = v;
        }
    }
}

// ---------------------------------------------------------------------------
// attn7: kt-split flash attention (R9/R10). unroll-2 on the kt loop so the
// double-buffer index `cur` folds to literals.
// ---------------------------------------------------------------------------
__global__ __launch_bounds__(512) void attn7(const u16* __restrict__ Q,
                                             const u16* __restrict__ K,
                                             const u16* __restrict__ Vt,
                                             u16* __restrict__ O)
{
    __shared__ __align__(16) short Kb[2][2][64 * 64];  // [g][buf] 32 KB
    __shared__ __align__(16) short Vb[2][2][64 * 64];  // [g][buf] 32 KB

    const int tid  = threadIdx.x;
    const int w    = tid >> 6;
    const int g    = w >> 2;         // kt-half
    const int wl   = w & 3;          // wave-in-group
    const int lane = tid & 63;
    const int ln   = lane & 15;
    const int q    = lane >> 4;
    const int lx   = ln & 7;
    const int bid  = blockIdx.x;
    const int bh   = bid & 31;
    const int qt   = bid >> 5;                // 0..15
    const int row0 = qt * 128 + wl * 32;
    const size_t sbase = (size_t)bh * NSEQ;
    const size_t vbase = (size_t)bh * DHEAD;
    const int kt0 = g * 16;

    const int rsub = lane >> 3;
    const int swz  = (lane & 7) ^ (rsub & 7);

    const intx4 onesi = {0x3F803F80, 0x3F803F80, 0x3F803F80, 0x3F803F80};
    const short8 ones = __builtin_bit_cast(short8, onesi);

    short8 bq[2][2];
#pragma unroll
    for (int mt = 0; mt < 2; ++mt)
#pragma unroll
        for (int kk = 0; kk < 2; ++kk)
            bq[mt][kk] = *(const short8*)&Q[(sbase + row0 + mt * 16 + ln) * DHEAD + kk * 32 + q * 8];

    floatx4 zero = {0.f, 0.f, 0.f, 0.f};
    floatx4 o[2][4];
    floatx4 ol[2];
#pragma unroll
    for (int mt = 0; mt < 2; ++mt) {
        ol[mt] = zero;
#pragma unroll
        for (int dt = 0; dt < 4; ++dt) o[mt][dt] = zero;
    }

    // stage this group's tile 0
#pragma unroll
    for (int i = 0; i < 2; ++i) {
        const int c = wl * 2 + i;
        const int row = c * 8 + rsub;
        gl_lds16(&K [(sbase + kt0 * 64 + row) * DHEAD + swz * 8], &Kb[g][0][c * 512]);
        gl_lds16(&Vt[(vbase + row) * NSEQ + kt0 * 64 + swz * 8],  &Vb[g][0][c * 512]);
    }

#pragma unroll 2
    for (int it = 0; it < 16; ++it) {
        __syncthreads();
        const int cur = it & 1;
        if (it + 1 < 16) {
            const int kb = (kt0 + it + 1) * 64;
#pragma unroll
            for (int i = 0; i < 2; ++i) {
                const int c = wl * 2 + i;
                const int row = c * 8 + rsub;
                gl_lds16(&K [(sbase + kb + row) * DHEAD + swz * 8], &Kb[g][cur ^ 1][c * 512]);
                gl_lds16(&Vt[(vbase + row) * NSEQ + kb + swz * 8],  &Vb[g][cur ^ 1][c * 512]);
            }
        }

        floatx4 st[4][2];
#pragma unroll
        for (int t = 0; t < 4; ++t) {
            short8 ak0 = *(short8*)&Kb[g][cur][(t * 16 + ln) * 64 + ((q ^ lx) * 8)];
            short8 ak1 = *(short8*)&Kb[g][cur][(t * 16 + ln) * 64 + (((4 + q) ^ lx) * 8)];
#pragma unroll
            for (int mt = 0; mt < 2; ++mt) {
                st[t][mt] = zero;
                st[t][mt] = __builtin_amdgcn_mfma_f32_16x16x32_bf16(ak0, bq[mt][0], st[t][mt], 0, 0, 0);
                st[t][mt] = __builtin_amdgcn_mfma_f32_16x16x32_bf16(ak1, bq[mt][1], st[t][mt], 0, 0, 0);
            }
        }

        intx4 bp[2][2];
#pragma unroll
        for (int mt = 0; mt < 2; ++mt) {
#pragma unroll
            for (int t = 0; t < 4; ++t) {
                floatx4 p;
#pragma unroll
                for (int r = 0; r < 4; ++r) p[r] = fexp2(st[t][mt][r]);
                bp[t >> 1][mt][(t & 1) * 2 + 0] = (int)pkbf(p[0], p[1]);
                bp[t >> 1][mt][(t & 1) * 2 + 1] = (int)pkbf(p[2], p[3]);
            }
        }

#pragma unroll
        for (int mt = 0; mt < 2; ++mt)
#pragma unroll
            for (int c = 0; c < 2; ++c)
                ol[mt] = __builtin_amdgcn_mfma_f32_16x16x32_bf16(
                    ones, __builtin_bit_cast(short8, bp[c][mt]), ol[mt], 0, 0, 0);

#pragma unroll
        for (int dt = 0; dt < 4; ++dt) {
#pragma unroll
            for (int c = 0; c < 2; ++c) {
                short8 av = *(short8*)&Vb[g][cur][(dt * 16 + ln) * 64 + (((4 * c + q) ^ lx) * 8)];
#pragma unroll
                for (int mt = 0; mt < 2; ++mt)
                    o[mt][dt] = __builtin_amdgcn_mfma_f32_16x16x32_bf16(
                        av, __builtin_bit_cast(short8, bp[c][mt]), o[mt][dt], 0, 0, 0);
            }
        }
    }

    // ---- combine the two kt-halves via LDS (exact: plain sums) ----
    __syncthreads();
    float* of = (float*)&Kb[0][0][0];
    float* lf = (float*)&Vb[1][1][0];
    if (g == 1) {
#pragma unroll
        for (int mt = 0; mt < 2; ++mt) {
#pragma unroll
            for (int dt = 0; dt < 4; ++dt)
                *(floatx4*)&of[(wl * 32 + mt * 16 + ln) * 68 + dt * 16 + q * 4] = o[mt][dt];
            lf[wl * 32 + mt * 16 + ln] = ol[mt][0];
        }
    }
    __syncthreads();
    if (g == 0) {
        const int b = bh >> 4, h = bh & 15;
        float l[2];
#pragma unroll
        for (int mt = 0; mt < 2; ++mt)
            l[mt] = frcp(ol[mt][0] + lf[wl * 32 + mt * 16 + ln]);
#pragma unroll
        for (int mt = 0; mt < 2; ++mt) {
            const int tok = row0 + mt * 16 + ln;
#pragma unroll
            for (int dt = 0; dt < 4; ++dt) {
                floatx4 p = *(floatx4*)&of[(wl * 32 + mt * 16 + ln) * 68 + dt * 16 + q * 4];
                uintx2 pk;
                pk[0] = pkbf((o[mt][dt][0] + p[0]) * l[mt], (o[mt][dt][1] + p[1]) * l[mt]);
                pk[1] = pkbf((o[mt][dt][2] + p[2]) * l[mt], (o[mt][dt][3] + p[3]) * l[mt]);
                *(uintx2*)&O[((size_t)(b * NSEQ + tok)) * DMODEL + h * DHEAD + dt * 16 + q * 4] = pk;
            }
        }
    }
}

// ---------------------------------------------------------------------------
// Fallback small-tile GEMM (fp32 staging) — used only if ws too small.
// ---------------------------------------------------------------------------
template <int MODE, typename TA, typename TB>
__global__ __launch_bounds__(256) void gemm_bt(const TA* __restrict__ A,
                                               const TB* __restrict__ B,
                                               const float* __restrict__ bias,
                                               void* __restrict__ Cv,
                                               float oscale)
{
    __shared__ __align__(16) short As[64][72];
    __shared__ __align__(16) short Bs[64][72];

    const int tid  = threadIdx.x;
    const int w    = tid >> 6;
    const int lane = tid & 63;
    const int ln   = lane & 15;
    const int q    = lane >> 4;
    const int wm   = w >> 1;
    const int wn   = w & 1;
    const int m0   = blockIdx.y * 64;
    const int n0   = blockIdx.x * 64;
    const int r    = tid >> 3;
    const int c8   = (tid & 7) * 8;

    floatx4 zero = {0.f, 0.f, 0.f, 0.f};
    floatx4 acc[2][2];
    acc[0][0] = zero; acc[0][1] = zero; acc[1][0] = zero; acc[1][1] = zero;

    for (int k0 = 0; k0 < DMODEL; k0 += 64) {
        *(short8*)&As[r][c8]      = ld8(&A[(size_t)(m0 + r) * DMODEL + k0 + c8]);
        *(short8*)&As[r + 32][c8] = ld8(&A[(size_t)(m0 + r + 32) * DMODEL + k0 + c8]);
        *(short8*)&Bs[r][c8]      = ld8(&B[(size_t)(n0 + r) * DMODEL + k0 + c8]);
        *(short8*)&Bs[r + 32][c8] = ld8(&B[(size_t)(n0 + r + 32) * DMODEL + k0 + c8]);
        __syncthreads();
#pragma unroll
        for (int kk = 0; kk < 2; ++kk) {
            short8 a0 = *(short8*)&As[wm * 32 + ln][kk * 32 + q * 8];
            short8 a1 = *(short8*)&As[wm * 32 + 16 + ln][kk * 32 + q * 8];
            short8 b0 = *(short8*)&Bs[wn * 32 + ln][kk * 32 + q * 8];
            short8 b1 = *(short8*)&Bs[wn * 32 + 16 + ln][kk * 32 + q * 8];
            acc[0][0] = __builtin_amdgcn_mfma_f32_16x16x32_bf16(a0, b0, acc[0][0], 0, 0, 0);
            acc[0][1] = __builtin_amdgcn_mfma_f32_16x16x32_bf16(a0, b1, acc[0][1], 0, 0, 0);
            acc[1][0] = __builtin_amdgcn_mfma_f32_16x16x32_bf16(a1, b0, acc[1][0], 0, 0, 0);
            acc[1][1] = __builtin_amdgcn_mfma_f32_16x16x32_bf16(a1, b1, acc[1][1], 0, 0, 0);
        }
        __syncthreads();
    }

#pragma unroll
    for (int mt = 0; mt < 2; ++mt) {
#pragma unroll
        for (int nt = 0; nt < 2; ++nt) {
            const int coln = wn * 32 + nt * 16 + ln;
            float bval = 0.f;
            if (MODE == 0) bval = bias[n0 + coln];
#pragma unroll
            for (int reg = 0; reg < 4; ++reg) {
                const int grow = m0 + wm * 32 + mt * 16 + q * 4 + reg;
                const float v = acc[mt][nt][reg] * oscale + bval;
                if (MODE == 0) {
                    ((float*)Cv)[(size_t)grow * DMODEL + n0 + coln] = v;
                } else {
                    const int b = grow >> 11, tok = grow & 2047, h = n0 >> 6;
                    if (MODE == 1)
                        ((u16*)Cv)[((size_t)(b * NH + h) * NSEQ + tok) * DHEAD + coln] = f2bf(v);
                    else {
                        const int tokp = (tok & ~63) + jperm(tok & 63);
                        ((u16*)Cv)[((size_t)(b * NH + h) * DHEAD + coln) * NSEQ + tokp] = f2bf(v);
                    }
                }
            }
        }
    }
}

// ---------------------------------------------------------------------------
extern "C" void kernel_launch(void* const* d_in, const int* in_sizes, int n_in,
                              void* d_out, int out_size, void* d_ws, size_t ws_size,
                              hipStream_t stream) {
    (void)in_sizes; (void)n_in; (void)out_size;
    const float* x  = (const float*)d_in[0];
    const float* Wq = (const float*)d_in[1];
    const float* Wk = (const float*)d_in[2];
    const float* Wv = (const float*)d_in[3];
    const float* Wo = (const float*)d_in[4];
    const float* bo = (const float*)d_in[5];
    float* out = (float*)d_out;

    dim3 bb(256);
    dim3 ba(512);   // attn7 block = 8 waves
    dim3 ga(512);   // attention grid: bh = bid&31 (XCD affinity), qt = bid>>5

    const size_t NEED = XN * 2 + 4 * WN * 2 + 3 * XN * 2;
    if (ws_size >= NEED) {
        u16* xb  = (u16*)d_ws;
        u16* Wqb = xb + XN;
        u16* Wkb = Wqb + WN;
        u16* Wvb = Wkb + WN;
        u16* Wob = Wvb + WN;
        u16* Qb  = Wob + WN;
        u16* Kb  = Qb + XN;
        u16* Vtb = Kb + XN;
        u16* Ob  = xb;

        cvt_all<<<dim3((unsigned)((XN + 4 * WN) / 8 / 256)), bb, 0, stream>>>(
            x, Wq, Wk, Wv, Wo, xb, Wqb, Wkb, Wvb, Wob);

        gemm_qkv<<<dim3(24, 32), bb, 0, stream>>>(xb, Wqb, Wkb, Wvb, Qb, Kb, Vtb);
        attn7<<<ga, ba, 0, stream>>>(Qb, Kb, Vtb, Ob);
        gemm_op<<<dim3(32, 16), bb, 0, stream>>>(Wob, Ob, bo, out);
    } else {
        u16* Qb  = (u16*)d_ws;
        u16* Kb  = Qb + XN;
        u16* Vtb = Kb + XN;
        u16* Ob  = Vtb + XN;
        dim3 gg(DMODEL / 64, MTOT / 64);
        gemm_bt<1, float, float><<<gg, bb, 0, stream>>>(x, Wq, nullptr, Qb, QSCALE);
        gemm_bt<1, float, float><<<gg, bb, 0, stream>>>(x, Wk, nullptr, Kb, 1.0f);
        gemm_bt<2, float, float><<<gg, bb, 0, stream>>>(x, Wv, nullptr, Vtb, 1.0f);
        attn7<<<ga, ba, 0, stream>>>(Qb, Kb, Vtb, Ob);
        gemm_bt<0, u16, float><<<gg, bb, 0, stream>>>(Ob, Wo, bo, out, 1.0f);
    }
}